// Round 3
// baseline (1246.299 us; speedup 1.0000x reference)
//
#include <hip/hip_runtime.h>

// Net_17532056502451 round 3: Gram-matrix reformulation of the encoder-conv.
// energy[s] = ||b||^2 + 2*sum_k y[k]*u[c0+k] + sum_{k,k'} y[k]y[k']G[c0+k][c0+k'],
// c0 = 80-s, G = Wt^T Wt (160x160, precomputed once), u = Wt . b_enc.
//
// ws layout (floats):
#define WS_XRES   0
#define WS_YRES   81920
#define WS_WT     163840   // Wt[c*512+f] = W_enc[f*160+c]
#define WS_WST    245760   // Wst[f*160+o] = W_src[o*512+f]
#define WS_G      327680   // G padded [160][164]
#define WS_U      353920   // u[160]
#define WS_BB     354080
#define WS_K      354081
#define WS_LOSS   354082   // 5 raw sq-sums (atomic)

#define GPITCH 164

// dynamic LDS float offsets
#define OFF_G    0        // 160*164 = 26240
#define OFF_YA   26240    // 4*84
#define OFF_XR   26576    // 320
#define OFF_YR   26896    // 320
#define OFF_XE   27216    // 320
#define OFF_SIM  27536    // 4*160
#define OFF_EN   28176    // 4*84
#define OFF_BE   28512    // 512
#define OFF_U    29024    // 160
#define LDS_FLOATS 29184  // 116736 bytes

__global__ void k_init(const float* __restrict__ x, const float* __restrict__ y,
                       const float* __restrict__ Wenc, const float* __restrict__ Wsrc,
                       float* __restrict__ ws) {
    int i = blockIdx.x * 256 + threadIdx.x;   // covers 81920
    ws[WS_XRES + i] = x[i];
    ws[WS_YRES + i] = y[i];
    int f = i / 160, c = i - f * 160;
    ws[WS_WT + c * 512 + f] = Wenc[i];
    int o = i >> 9, f2 = i & 511;
    ws[WS_WST + f2 * 160 + o] = Wsrc[i];
}

__device__ __forceinline__ float wave_sum(float v) {
    for (int d = 32; d > 0; d >>= 1) v += __shfl_down(v, d);
    return __shfl(v, 0);
}
__device__ __forceinline__ float wave_max(float v) {
    for (int d = 32; d > 0; d >>= 1) v = fmaxf(v, __shfl_down(v, d));
    return __shfl(v, 0);
}
__device__ __forceinline__ int wave_argmax(float v, int i) {
    for (int d = 32; d > 0; d >>= 1) {
        float v2 = __shfl_down(v, d);
        int   i2 = __shfl_down(i, d);
        if (v2 > v || (v2 == v && i2 < i)) { v = v2; i = i2; }
    }
    return __shfl(i, 0);
}

// G precompute (161 blocks): b<160 -> G row b; b==160 -> u, bb, K, zero losses.
__global__ __launch_bounds__(256)
void k_pre(const float* __restrict__ y, const float* __restrict__ benc,
           float* __restrict__ ws) {
    const int b = blockIdx.x, tid = threadIdx.x;
    const int wv = tid >> 6, lane = tid & 63;
    if (b < 160) {
        __shared__ float wr[512];
        if (tid < 128) ((float4*)wr)[tid] = ((const float4*)(ws + WS_WT + b * 512))[tid];
        __syncthreads();
        for (int cg = 0; cg < 160; cg += 4) {
            int c = cg + wv;
            const float* Wc = ws + WS_WT + c * 512;
            float a = 0.0f;
#pragma unroll
            for (int jj = 0; jj < 8; ++jj) {
                int f = lane + 64 * jj;
                a = fmaf(wr[f], Wc[f], a);
            }
            a = wave_sum(a);
            if (lane == 0) ws[WS_G + b * GPITCH + c] = a;
        }
    } else {
        // u[c] = sum_f benc[f] * Wt[c*512+f]
        for (int cg = 0; cg < 160; cg += 4) {
            int c = cg + wv;
            const float* Wc = ws + WS_WT + c * 512;
            float a = 0.0f;
#pragma unroll
            for (int jj = 0; jj < 8; ++jj) {
                int f = lane + 64 * jj;
                a = fmaf(benc[f], Wc[f], a);
            }
            a = wave_sum(a);
            if (lane == 0) ws[WS_U + c] = a;
        }
        if (wv == 0) {
            float a = 0.0f;
#pragma unroll
            for (int jj = 0; jj < 8; ++jj) {
                float bv = benc[lane + 64 * jj];
                a = fmaf(bv, bv, a);
            }
            a = wave_sum(a);
            if (lane == 0) ws[WS_BB] = a;
        }
        __shared__ int red[256];
        int cnt = 0;
        for (int i = tid; i < 81920; i += 256) cnt += (y[i] != 0.0f) ? 1 : 0;
        red[tid] = cnt;
        __syncthreads();
        for (int s = 128; s > 0; s >>= 1) {
            if (tid < s) red[tid] += red[tid + s];
            __syncthreads();
        }
        if (tid == 0) { int k = red[0]; ws[WS_K] = (float)(k < 1 ? 1 : k); }
        if (tid < 5) ws[WS_LOSS + tid] = 0.0f;
    }
}

// Quadratic-form conv for one wave: s in {s0, s0+4, ..., <=80}, U = c0 & 3 (static).
template<int U>
__device__ __forceinline__ void conv_run(const float* __restrict__ Glds,
                                         const float* __restrict__ ya_l,
                                         const float* __restrict__ u_l,
                                         float* __restrict__ energy,
                                         const float (&yreg)[80],
                                         int kl, int pos, int s0, float bbv) {
    for (int s = s0; s <= 80; s += 4) {
        const int c0 = 80 - s;
        const int a0 = c0 - U;          // aligned col base (c0 mod 4 == U)
        float vs[5];
#pragma unroll
        for (int m = 0; m < 5; ++m) {
            const int r = c0 + 5 * kl + m;
            const float* gp = Glds + r * GPITCH + a0;
            float acc = 0.0f;
#pragma unroll
            for (int t = 0; t <= 20; ++t) {
                if (4 * t - U > 79) break;               // constexpr-folded
                float4 g = *(const float4*)(gp + 4 * t);
                const float gq[4] = {g.x, g.y, g.z, g.w};
#pragma unroll
                for (int q = 0; q < 4; ++q) {
                    const int j = 4 * t + q - U;
                    if (j >= 0 && j < 80) acc = fmaf(gq[q], yreg[j], acc);
                }
            }
            vs[m] = acc;
        }
        float e = 0.0f;
#pragma unroll
        for (int m = 0; m < 5; ++m) {
            const int k = 5 * kl + m;
            e += ya_l[pos * 84 + k] * (vs[m] + 2.0f * u_l[c0 + k]);
        }
        e += __shfl_xor(e, 4);
        e += __shfl_xor(e, 8);
        e += __shfl_xor(e, 16);
        e += __shfl_xor(e, 32);
        if (kl == 0) energy[pos * 84 + s] = bbv + e;
    }
}

__global__ __launch_bounds__(256, 1)
void k_iter(const float* __restrict__ yorig,
            const float* __restrict__ benc, const float* __restrict__ bsrc,
            float* __restrict__ ws, int it) {
    float* xres = ws + WS_XRES;
    float* yres = ws + WS_YRES;
    const float* Wt  = ws + WS_WT;
    const float* Wst = ws + WS_WST;

    extern __shared__ float lds[];
    float* Glds  = lds + OFF_G;
    float* ya_l  = lds + OFF_YA;
    float* xr    = lds + OFF_XR;
    float* yr    = lds + OFF_YR;
    float* xele  = lds + OFF_XE;
    float* simS  = lds + OFF_SIM;
    float* energy= lds + OFF_EN;
    float* sbenc = lds + OFF_BE;
    float* u_l   = lds + OFF_U;

    __shared__ float s_ny2[4], s_sq[4], s_bb;
    __shared__ int   s_hind[4];

    const int tid  = threadIdx.x;
    const int lane = tid & 63;
    const int wv   = tid >> 6;
    const int base = blockIdx.x * 320;

    // ---- stage: residuals, benc, u, bb, G ----
    for (int i = tid; i < 320; i += 256) { xr[i] = xres[base + i]; yr[i] = yres[base + i]; }
    sbenc[tid] = benc[tid];
    sbenc[tid + 256] = benc[tid + 256];
    if (tid < 160) u_l[tid] = ws[WS_U + tid];
    if (tid == 0) s_bb = ws[WS_BB];
    {
        const float4* Gg = (const float4*)(ws + WS_G);
        float4* Gl = (float4*)Glds;
        for (int idx = tid; idx < 6560; idx += 256) Gl[idx] = Gg[idx];   // 160*41 float4
    }
    __syncthreads();

    // ---- ||y||^2 per position ----
    {
        float a = yr[wv * 80 + lane];
        float v = a * a;
        if (lane < 16) { float u = yr[wv * 80 + 64 + lane]; v = fmaf(u, u, v); }
        v = wave_sum(v);
        if (lane == 0) s_ny2[wv] = v;
    }
    __syncthreads();

    // ---- cosine sim over 159 shifts x 4 positions ----
    for (int t = tid; t < 636; t += 256) {
        int pp = t / 159, s = t - pp * 159;
        int ilo = (s - 79 > 0) ? s - 79 : 0;
        int ihi = (s < 79) ? s : 79;
        const float* xp = xr + pp * 80;
        const float* yp = yr + pp * 80;
        float dot = 0.0f, nx2 = 0.0f;
        for (int i = ilo; i <= ihi; ++i) {
            float xv = xp[i];
            dot = fmaf(xv, yp[i - s + 79], dot);
            nx2 = fmaf(xv, xv, nx2);
        }
        float denom = sqrtf(nx2) * sqrtf(s_ny2[pp]);
        simS[pp * 160 + s] = (denom == 0.0f) ? 0.0f : dot / denom;
    }
    __syncthreads();

    // ---- theta argmax + softmax attention -> ya_l, xele (per wave) ----
    int theta;
    {
        float v = simS[wv * 160 + lane]; int i = lane;
        { float v2 = simS[wv * 160 + lane + 64]; int i2 = lane + 64;
          if (v2 > v || (v2 == v && i2 < i)) { v = v2; i = i2; } }
        if (lane < 31) {
            float v2 = simS[wv * 160 + lane + 128]; int i2 = lane + 128;
            if (v2 > v || (v2 == v && i2 < i)) { v = v2; i = i2; }
        }
        theta = wave_argmax(v, i);
    }
    {
        const float* xp = xr + wv * 80;
        const float* yp = yr + wv * 80;
        int t0 = lane, t1 = lane + 64;
        int ix0 = theta + t0 - 79;
        float ya0 = (ix0 >= 0 && ix0 < 80) ? xp[ix0] : 0.0f;
        float z0 = ya0 * yp[t0] / 0.7f;
        float ya1 = 0.0f, z1 = -INFINITY;
        if (t1 < 80) {
            int ix1 = theta + t1 - 79;
            ya1 = (ix1 >= 0 && ix1 < 80) ? xp[ix1] : 0.0f;
            z1 = ya1 * yp[t1] / 0.7f;
        }
        float m = wave_max(fmaxf(z0, z1));
        float e0 = expf(z0 - m);
        float e1 = (t1 < 80) ? expf(z1 - m) : 0.0f;
        float S = wave_sum(e0 + e1);
        ya_l[wv * 84 + t0] = ya0 * (e0 / S);
        if (t1 < 80) ya_l[wv * 84 + t1] = ya1 * (e1 / S);
    }
    {
        int t0 = lane, t1 = lane + 64;
        int k0 = 79 - theta + t0;
        xele[wv * 80 + t0] = (k0 >= 0 && k0 < 80) ? ya_l[wv * 84 + k0] : 0.0f;
        if (t1 < 80) {
            int k1 = 79 - theta + t1;
            xele[wv * 80 + t1] = (k1 >= 0 && k1 < 80) ? ya_l[wv * 84 + k1] : 0.0f;
        }
    }
    __syncthreads();

    // ---- quadratic-form conv: lane = kl*4 + pos; wave w handles s === w (mod 4) ----
    {
        const int kl = lane >> 2, pos = lane & 3;
        float yreg[80];
#pragma unroll
        for (int t = 0; t < 20; ++t) {
            float4 v = *(const float4*)(ya_l + pos * 84 + 4 * t);
            yreg[4 * t + 0] = v.x; yreg[4 * t + 1] = v.y;
            yreg[4 * t + 2] = v.z; yreg[4 * t + 3] = v.w;
        }
        const float bbv = s_bb;
        switch (wv) {
            case 0: conv_run<0>(Glds, ya_l, u_l, energy, yreg, kl, pos, 0, bbv); break;
            case 1: conv_run<3>(Glds, ya_l, u_l, energy, yreg, kl, pos, 1, bbv); break;
            case 2: conv_run<2>(Glds, ya_l, u_l, energy, yreg, kl, pos, 2, bbv); break;
            default: conv_run<1>(Glds, ya_l, u_l, energy, yreg, kl, pos, 3, bbv); break;
        }
    }
    __syncthreads();

    // ---- h_ind argmax per wave ----
    {
        float v = energy[wv * 84 + lane]; int i = lane;
        if (lane < 17) {
            float v2 = energy[wv * 84 + lane + 64]; int i2 = lane + 64;
            if (v2 > v || (v2 == v && i2 < i)) { v = v2; i = i2; }
        }
        int hind = wave_argmax(v, i);
        if (lane == 0) s_hind[wv] = hind;
    }
    __syncthreads();

    float* hselL = lds;          // overlay into dead G region
    float* xextL = lds + 2048;

    // ---- recompute h_sel rows (coalesced over f, global Wt in L2) ----
    for (int t = tid; t < 2048; t += 256) {
        int pp = t >> 9, f = t & 511;
        int cb = 80 - s_hind[pp];
        const float* Wp = Wt + cb * 512 + f;
        const float* yap = ya_l + pp * 84;
        float a0 = sbenc[f], a1 = 0.0f, a2 = 0.0f, a3 = 0.0f;
        for (int k = 0; k < 80; k += 4) {
            a0 = fmaf(yap[k],     Wp[k * 512],       a0);
            a1 = fmaf(yap[k + 1], Wp[(k + 1) * 512], a1);
            a2 = fmaf(yap[k + 2], Wp[(k + 2) * 512], a2);
            a3 = fmaf(yap[k + 3], Wp[(k + 3) * 512], a3);
        }
        hselL[t] = (a0 + a1) + (a2 + a3);
    }
    __syncthreads();

    // ---- decoder GEMV ----
    for (int t = tid; t < 640; t += 256) {
        int pp = t / 160, o = t - pp * 160;
        const float* hp = hselL + pp * 512;
        const float* W = Wst + o;
        float a0 = bsrc[o], a1 = 0.0f, a2 = 0.0f, a3 = 0.0f;
        for (int f = 0; f < 512; f += 4) {
            a0 = fmaf(hp[f],     W[f * 160],       a0);
            a1 = fmaf(hp[f + 1], W[(f + 1) * 160], a1);
            a2 = fmaf(hp[f + 2], W[(f + 2) * 160], a2);
            a3 = fmaf(hp[f + 3], W[(f + 3) * 160], a3);
        }
        xextL[t] = (a0 + a1) + (a2 + a3);
    }
    __syncthreads();

    // ---- loss + residual update per wave ----
    {
        int hd = s_hind[wv];
        int t0 = lane, t1 = lane + 64;
        float sq;
        {
            float yele = xextL[wv * 160 + 80 - hd + t0];
            float yv = yr[wv * 80 + t0];
            float keep = (yorig[base + wv * 80 + t0] != 0.0f) ? 1.0f : 0.0f;
            float d = yele - yv;
            sq = d * d * keep;
            yres[base + wv * 80 + t0] = yv - yele;
            xres[base + wv * 80 + t0] = xr[wv * 80 + t0] - xele[wv * 80 + t0];
        }
        if (t1 < 80) {
            float yele = xextL[wv * 160 + 80 - hd + t1];
            float yv = yr[wv * 80 + t1];
            float keep = (yorig[base + wv * 80 + t1] != 0.0f) ? 1.0f : 0.0f;
            float d = yele - yv;
            sq = fmaf(d * keep, d, sq);
            yres[base + wv * 80 + t1] = yv - yele;
            xres[base + wv * 80 + t1] = xr[wv * 80 + t1] - xele[wv * 80 + t1];
        }
        sq = wave_sum(sq);
        if (lane == 0) s_sq[wv] = sq;
    }
    __syncthreads();
    if (tid == 0)
        atomicAdd(&ws[WS_LOSS + it], (s_sq[0] + s_sq[1]) + (s_sq[2] + s_sq[3]));
}

__global__ void k_final(const float* __restrict__ ws, float* __restrict__ out) {
    float K = ws[WS_K];
    out[0] = (ws[WS_LOSS] + ws[WS_LOSS + 1] + ws[WS_LOSS + 2] +
              ws[WS_LOSS + 3] + ws[WS_LOSS + 4]) / (K * 5.0f);
}

extern "C" void kernel_launch(void* const* d_in, const int* in_sizes, int n_in,
                              void* d_out, int out_size, void* d_ws, size_t ws_size,
                              hipStream_t stream) {
    const float* x    = (const float*)d_in[0];
    const float* y    = (const float*)d_in[1];
    const float* Wenc = (const float*)d_in[2];
    const float* benc = (const float*)d_in[3];
    const float* Wsrc = (const float*)d_in[4];
    const float* bsrc = (const float*)d_in[5];
    float* ws  = (float*)d_ws;
    float* out = (float*)d_out;

    (void)hipFuncSetAttribute((const void*)k_iter,
                              hipFuncAttributeMaxDynamicSharedMemorySize,
                              LDS_FLOATS * 4);

    k_init<<<320, 256, 0, stream>>>(x, y, Wenc, Wsrc, ws);
    k_pre<<<161, 256, 0, stream>>>(y, benc, ws);
    for (int it = 0; it < 5; ++it)
        k_iter<<<256, 256, LDS_FLOATS * 4, stream>>>(y, benc, bsrc, ws, it);
    k_final<<<1, 1, 0, stream>>>(ws, out);
}

// Round 4
// 1179.397 us; speedup vs baseline: 1.0567x; 1.0567x over previous
//
#include <hip/hip_runtime.h>

// Net_17532056502451 round 4: Gram-matrix conv, register-safe inner loop.
// energy[s] = ||b||^2 + sum_k y[k]*(2u[c0+k] + sum_j G[c0+k][c0+j] y[j]), c0=80-s.
// 512 thr/block, 8 waves: wave w handles s === w (mod 8); lane = kl*4+pos.
//
// ws layout (floats):
#define WS_XRES   0
#define WS_YRES   81920
#define WS_WT     163840   // Wt[c*512+f] = W_enc[f*160+c]
#define WS_WST    245760   // Wst[f*160+o] = W_src[o*512+f]
#define WS_G      327680   // G padded [160][164]
#define WS_U      353920   // u[160]
#define WS_BB     354080
#define WS_K      354081
#define WS_LOSS   354082   // 5 raw sq-sums (atomic)

#define GPITCH 164

// dynamic LDS float offsets
#define OFF_G    0        // 160*164 = 26240
#define OFF_YA   26240    // 4*84
#define OFF_XR   26576    // 320
#define OFF_YR   26896    // 320
#define OFF_XE   27216    // 320
#define OFF_SIM  27536    // 4*160
#define OFF_EN   28176    // 4*84
#define OFF_BE   28512    // 512
#define OFF_U    29024    // 160
#define LDS_FLOATS 29184  // 116736 bytes

__global__ void k_init(const float* __restrict__ x, const float* __restrict__ y,
                       const float* __restrict__ Wenc, const float* __restrict__ Wsrc,
                       float* __restrict__ ws) {
    int i = blockIdx.x * 256 + threadIdx.x;   // covers 81920
    ws[WS_XRES + i] = x[i];
    ws[WS_YRES + i] = y[i];
    int f = i / 160, c = i - f * 160;
    ws[WS_WT + c * 512 + f] = Wenc[i];
    int o = i >> 9, f2 = i & 511;
    ws[WS_WST + f2 * 160 + o] = Wsrc[i];
}

__device__ __forceinline__ float wave_sum(float v) {
    for (int d = 32; d > 0; d >>= 1) v += __shfl_down(v, d);
    return __shfl(v, 0);
}
__device__ __forceinline__ float wave_max(float v) {
    for (int d = 32; d > 0; d >>= 1) v = fmaxf(v, __shfl_down(v, d));
    return __shfl(v, 0);
}
__device__ __forceinline__ int wave_argmax(float v, int i) {
    for (int d = 32; d > 0; d >>= 1) {
        float v2 = __shfl_down(v, d);
        int   i2 = __shfl_down(i, d);
        if (v2 > v || (v2 == v && i2 < i)) { v = v2; i = i2; }
    }
    return __shfl(i, 0);
}

// G precompute (161 blocks): b<160 -> G row b; b==160 -> u, bb, K, zero losses.
__global__ __launch_bounds__(256)
void k_pre(const float* __restrict__ y, const float* __restrict__ benc,
           float* __restrict__ ws) {
    const int b = blockIdx.x, tid = threadIdx.x;
    const int wv = tid >> 6, lane = tid & 63;
    if (b < 160) {
        __shared__ float wr[512];
        if (tid < 128) ((float4*)wr)[tid] = ((const float4*)(ws + WS_WT + b * 512))[tid];
        __syncthreads();
        for (int cg = 0; cg < 160; cg += 4) {
            int c = cg + wv;
            const float* Wc = ws + WS_WT + c * 512;
            float a = 0.0f;
#pragma unroll
            for (int jj = 0; jj < 8; ++jj) {
                int f = lane + 64 * jj;
                a = fmaf(wr[f], Wc[f], a);
            }
            a = wave_sum(a);
            if (lane == 0) ws[WS_G + b * GPITCH + c] = a;
        }
    } else {
        for (int cg = 0; cg < 160; cg += 4) {
            int c = cg + wv;
            const float* Wc = ws + WS_WT + c * 512;
            float a = 0.0f;
#pragma unroll
            for (int jj = 0; jj < 8; ++jj) {
                int f = lane + 64 * jj;
                a = fmaf(benc[f], Wc[f], a);
            }
            a = wave_sum(a);
            if (lane == 0) ws[WS_U + c] = a;
        }
        if (wv == 0) {
            float a = 0.0f;
#pragma unroll
            for (int jj = 0; jj < 8; ++jj) {
                float bv = benc[lane + 64 * jj];
                a = fmaf(bv, bv, a);
            }
            a = wave_sum(a);
            if (lane == 0) ws[WS_BB] = a;
        }
        __shared__ int red[256];
        int cnt = 0;
        for (int i = tid; i < 81920; i += 256) cnt += (y[i] != 0.0f) ? 1 : 0;
        red[tid] = cnt;
        __syncthreads();
        for (int s = 128; s > 0; s >>= 1) {
            if (tid < s) red[tid] += red[tid + s];
            __syncthreads();
        }
        if (tid == 0) { int k = red[0]; ws[WS_K] = (float)(k < 1 ? 1 : k); }
        if (tid < 5) ws[WS_LOSS + tid] = 0.0f;
    }
}

// Quadratic form for s in {s0, s0+8, ...}: register-safe (8-float window + 5 acc).
// Per-row sum order (t asc, q asc) identical to round-3 -> bit-identical energies.
template<int U>
__device__ __forceinline__ void conv_run(const float* __restrict__ Glds,
                                         const float* __restrict__ yp,   // ya_l + pos*84
                                         const float* __restrict__ u_l,
                                         float* __restrict__ energy,
                                         int kl, int pos, int s0, float bbv) {
    constexpr int TMAX = (U == 0) ? 20 : 21;
    for (int s = s0; s <= 80; s += 8) {
        const int c0 = 80 - s;
        const float* gp = Glds + (c0 + 5 * kl) * GPITCH + (c0 - U);
        float acc[5] = {0.f, 0.f, 0.f, 0.f, 0.f};
        float w[8];
        { float4 c = *(const float4*)yp; w[4] = c.x; w[5] = c.y; w[6] = c.z; w[7] = c.w; }
#pragma unroll
        for (int t = 0; t < TMAX; ++t) {
            if (t > 0) {
#pragma unroll
                for (int q = 0; q < 4; ++q) w[q] = w[q + 4];
                if (t <= 19) {
                    float4 c = *(const float4*)(yp + 4 * t);
                    w[4] = c.x; w[5] = c.y; w[6] = c.z; w[7] = c.w;
                }
            }
            float4 g0 = *(const float4*)(gp + 4 * t);
            float4 g1 = *(const float4*)(gp + GPITCH + 4 * t);
            float4 g2 = *(const float4*)(gp + 2 * GPITCH + 4 * t);
            float4 g3 = *(const float4*)(gp + 3 * GPITCH + 4 * t);
            float4 g4 = *(const float4*)(gp + 4 * GPITCH + 4 * t);
            const float gq0[4] = {g0.x, g0.y, g0.z, g0.w};
            const float gq1[4] = {g1.x, g1.y, g1.z, g1.w};
            const float gq2[4] = {g2.x, g2.y, g2.z, g2.w};
            const float gq3[4] = {g3.x, g3.y, g3.z, g3.w};
            const float gq4[4] = {g4.x, g4.y, g4.z, g4.w};
#pragma unroll
            for (int q = 0; q < 4; ++q) {
                const int j = 4 * t + q - U;          // constant after unroll
                if (j >= 0 && j <= 79) {
                    const float yv = w[4 + q - U];
                    acc[0] = fmaf(gq0[q], yv, acc[0]);
                    acc[1] = fmaf(gq1[q], yv, acc[1]);
                    acc[2] = fmaf(gq2[q], yv, acc[2]);
                    acc[3] = fmaf(gq3[q], yv, acc[3]);
                    acc[4] = fmaf(gq4[q], yv, acc[4]);
                }
            }
        }
        float e = 0.0f;
#pragma unroll
        for (int m = 0; m < 5; ++m) {
            const int k = 5 * kl + m;
            e += yp[k] * (acc[m] + 2.0f * u_l[c0 + k]);
        }
        e += __shfl_xor(e, 4);
        e += __shfl_xor(e, 8);
        e += __shfl_xor(e, 16);
        e += __shfl_xor(e, 32);
        if (kl == 0) energy[pos * 84 + s] = bbv + e;
    }
}

__global__ __launch_bounds__(512, 2)
void k_iter(const float* __restrict__ yorig,
            const float* __restrict__ benc, const float* __restrict__ bsrc,
            float* __restrict__ ws, int it) {
    float* xres = ws + WS_XRES;
    float* yres = ws + WS_YRES;
    const float* Wt  = ws + WS_WT;
    const float* Wst = ws + WS_WST;

    extern __shared__ float lds[];
    float* Glds  = lds + OFF_G;
    float* ya_l  = lds + OFF_YA;
    float* xr    = lds + OFF_XR;
    float* yr    = lds + OFF_YR;
    float* xele  = lds + OFF_XE;
    float* simS  = lds + OFF_SIM;
    float* energy= lds + OFF_EN;
    float* sbenc = lds + OFF_BE;
    float* u_l   = lds + OFF_U;

    __shared__ float s_ny2[4], s_sq[4], s_bb;
    __shared__ int   s_hind[4];

    const int tid  = threadIdx.x;
    const int lane = tid & 63;
    const int wv   = tid >> 6;          // 0..7
    const int base = blockIdx.x * 320;

    // ---- stage: residuals, benc, u, bb, G ----
    for (int i = tid; i < 320; i += 512) { xr[i] = xres[base + i]; yr[i] = yres[base + i]; }
    sbenc[tid] = benc[tid];
    if (tid < 160) u_l[tid] = ws[WS_U + tid];
    if (tid == 0) s_bb = ws[WS_BB];
    {
        const float4* Gg = (const float4*)(ws + WS_G);
        float4* Gl = (float4*)Glds;
        for (int idx = tid; idx < 6560; idx += 512) Gl[idx] = Gg[idx];
    }
    __syncthreads();

    // ---- ||y||^2 per position (waves 0..3) ----
    if (wv < 4) {
        float a = yr[wv * 80 + lane];
        float v = a * a;
        if (lane < 16) { float u = yr[wv * 80 + 64 + lane]; v = fmaf(u, u, v); }
        v = wave_sum(v);
        if (lane == 0) s_ny2[wv] = v;
    }
    __syncthreads();

    // ---- cosine sim over 159 shifts x 4 positions ----
    for (int t = tid; t < 636; t += 512) {
        int pp = t / 159, s = t - pp * 159;
        int ilo = (s - 79 > 0) ? s - 79 : 0;
        int ihi = (s < 79) ? s : 79;
        const float* xp = xr + pp * 80;
        const float* yp = yr + pp * 80;
        float dot = 0.0f, nx2 = 0.0f;
        for (int i = ilo; i <= ihi; ++i) {
            float xv = xp[i];
            dot = fmaf(xv, yp[i - s + 79], dot);
            nx2 = fmaf(xv, xv, nx2);
        }
        float denom = sqrtf(nx2) * sqrtf(s_ny2[pp]);
        simS[pp * 160 + s] = (denom == 0.0f) ? 0.0f : dot / denom;
    }
    __syncthreads();

    // ---- theta argmax + softmax attention -> ya_l, xele (waves 0..3) ----
    if (wv < 4) {
        int theta;
        {
            float v = simS[wv * 160 + lane]; int i = lane;
            { float v2 = simS[wv * 160 + lane + 64]; int i2 = lane + 64;
              if (v2 > v || (v2 == v && i2 < i)) { v = v2; i = i2; } }
            if (lane < 31) {
                float v2 = simS[wv * 160 + lane + 128]; int i2 = lane + 128;
                if (v2 > v || (v2 == v && i2 < i)) { v = v2; i = i2; }
            }
            theta = wave_argmax(v, i);
        }
        const float* xp = xr + wv * 80;
        const float* yp = yr + wv * 80;
        int t0 = lane, t1 = lane + 64;
        int ix0 = theta + t0 - 79;
        float ya0 = (ix0 >= 0 && ix0 < 80) ? xp[ix0] : 0.0f;
        float z0 = ya0 * yp[t0] / 0.7f;
        float ya1 = 0.0f, z1 = -INFINITY;
        if (t1 < 80) {
            int ix1 = theta + t1 - 79;
            ya1 = (ix1 >= 0 && ix1 < 80) ? xp[ix1] : 0.0f;
            z1 = ya1 * yp[t1] / 0.7f;
        }
        float m = wave_max(fmaxf(z0, z1));
        float e0 = expf(z0 - m);
        float e1 = (t1 < 80) ? expf(z1 - m) : 0.0f;
        float S = wave_sum(e0 + e1);
        ya_l[wv * 84 + t0] = ya0 * (e0 / S);
        if (t1 < 80) ya_l[wv * 84 + t1] = ya1 * (e1 / S);
        // xele (same wave wrote ya_l; wave-coherent)
        int k0 = 79 - theta + t0;
        xele[wv * 80 + t0] = (k0 >= 0 && k0 < 80) ? ya_l[wv * 84 + k0] : 0.0f;
        if (t1 < 80) {
            int k1 = 79 - theta + t1;
            xele[wv * 80 + t1] = (k1 >= 0 && k1 < 80) ? ya_l[wv * 84 + k1] : 0.0f;
        }
    }
    __syncthreads();

    // ---- quadratic-form conv: 8 waves, s === wv (mod 8); lane = kl*4 + pos ----
    {
        const int kl = lane >> 2, pos = lane & 3;
        const float* yp = ya_l + pos * 84;
        const float bbv = s_bb;
        switch (wv & 3) {
            case 0: conv_run<0>(Glds, yp, u_l, energy, kl, pos, wv, bbv); break;
            case 1: conv_run<3>(Glds, yp, u_l, energy, kl, pos, wv, bbv); break;
            case 2: conv_run<2>(Glds, yp, u_l, energy, kl, pos, wv, bbv); break;
            default: conv_run<1>(Glds, yp, u_l, energy, kl, pos, wv, bbv); break;
        }
    }
    __syncthreads();

    // ---- h_ind argmax per position (waves 0..3) ----
    if (wv < 4) {
        float v = energy[wv * 84 + lane]; int i = lane;
        if (lane < 17) {
            float v2 = energy[wv * 84 + lane + 64]; int i2 = lane + 64;
            if (v2 > v || (v2 == v && i2 < i)) { v = v2; i = i2; }
        }
        int hind = wave_argmax(v, i);
        if (lane == 0) s_hind[wv] = hind;
    }
    __syncthreads();

    float* hselL = lds;          // overlay into dead G region
    float* xextL = lds + 2048;

    // ---- recompute h_sel rows (coalesced over f, Wt in L2) ----
    for (int t = tid; t < 2048; t += 512) {
        int pp = t >> 9, f = t & 511;
        int cb = 80 - s_hind[pp];
        const float* Wp = Wt + cb * 512 + f;
        const float* yap = ya_l + pp * 84;
        float a0 = sbenc[f], a1 = 0.0f, a2 = 0.0f, a3 = 0.0f;
        for (int k = 0; k < 80; k += 4) {
            a0 = fmaf(yap[k],     Wp[k * 512],       a0);
            a1 = fmaf(yap[k + 1], Wp[(k + 1) * 512], a1);
            a2 = fmaf(yap[k + 2], Wp[(k + 2) * 512], a2);
            a3 = fmaf(yap[k + 3], Wp[(k + 3) * 512], a3);
        }
        hselL[t] = (a0 + a1) + (a2 + a3);
    }
    __syncthreads();

    // ---- decoder GEMV ----
    for (int t = tid; t < 640; t += 512) {
        int pp = t / 160, o = t - pp * 160;
        const float* hp = hselL + pp * 512;
        const float* W = Wst + o;
        float a0 = bsrc[o], a1 = 0.0f, a2 = 0.0f, a3 = 0.0f;
        for (int f = 0; f < 512; f += 4) {
            a0 = fmaf(hp[f],     W[f * 160],       a0);
            a1 = fmaf(hp[f + 1], W[(f + 1) * 160], a1);
            a2 = fmaf(hp[f + 2], W[(f + 2) * 160], a2);
            a3 = fmaf(hp[f + 3], W[(f + 3) * 160], a3);
        }
        xextL[t] = (a0 + a1) + (a2 + a3);
    }
    __syncthreads();

    // ---- loss + residual update per position (waves 0..3) ----
    if (wv < 4) {
        int hd = s_hind[wv];
        int t0 = lane, t1 = lane + 64;
        float sq;
        {
            float yele = xextL[wv * 160 + 80 - hd + t0];
            float yv = yr[wv * 80 + t0];
            float keep = (yorig[base + wv * 80 + t0] != 0.0f) ? 1.0f : 0.0f;
            float d = yele - yv;
            sq = d * d * keep;
            yres[base + wv * 80 + t0] = yv - yele;
            xres[base + wv * 80 + t0] = xr[wv * 80 + t0] - xele[wv * 80 + t0];
        }
        if (t1 < 80) {
            float yele = xextL[wv * 160 + 80 - hd + t1];
            float yv = yr[wv * 80 + t1];
            float keep = (yorig[base + wv * 80 + t1] != 0.0f) ? 1.0f : 0.0f;
            float d = yele - yv;
            sq = fmaf(d * keep, d, sq);
            yres[base + wv * 80 + t1] = yv - yele;
            xres[base + wv * 80 + t1] = xr[wv * 80 + t1] - xele[wv * 80 + t1];
        }
        sq = wave_sum(sq);
        if (lane == 0) s_sq[wv] = sq;
    }
    __syncthreads();
    if (tid == 0)
        atomicAdd(&ws[WS_LOSS + it], (s_sq[0] + s_sq[1]) + (s_sq[2] + s_sq[3]));
}

__global__ void k_final(const float* __restrict__ ws, float* __restrict__ out) {
    float K = ws[WS_K];
    out[0] = (ws[WS_LOSS] + ws[WS_LOSS + 1] + ws[WS_LOSS + 2] +
              ws[WS_LOSS + 3] + ws[WS_LOSS + 4]) / (K * 5.0f);
}

extern "C" void kernel_launch(void* const* d_in, const int* in_sizes, int n_in,
                              void* d_out, int out_size, void* d_ws, size_t ws_size,
                              hipStream_t stream) {
    const float* x    = (const float*)d_in[0];
    const float* y    = (const float*)d_in[1];
    const float* Wenc = (const float*)d_in[2];
    const float* benc = (const float*)d_in[3];
    const float* Wsrc = (const float*)d_in[4];
    const float* bsrc = (const float*)d_in[5];
    float* ws  = (float*)d_ws;
    float* out = (float*)d_out;

    (void)hipFuncSetAttribute((const void*)k_iter,
                              hipFuncAttributeMaxDynamicSharedMemorySize,
                              LDS_FLOATS * 4);

    k_init<<<320, 256, 0, stream>>>(x, y, Wenc, Wsrc, ws);
    k_pre<<<161, 256, 0, stream>>>(y, benc, ws);
    for (int it = 0; it < 5; ++it)
        k_iter<<<256, 512, LDS_FLOATS * 4, stream>>>(y, benc, bsrc, ws, it);
    k_final<<<1, 1, 0, stream>>>(ws, out);
}